// Round 3
// baseline (613.681 us; speedup 1.0000x reference)
//
#include <hip/hip_runtime.h>

typedef __bf16 bf16_t;
typedef bf16_t bf16x8 __attribute__((ext_vector_type(8)));
typedef bf16_t bf16x4 __attribute__((ext_vector_type(4)));
typedef float floatx4 __attribute__((ext_vector_type(4)));

static constexpr int NB  = 16;
static constexpr int NC  = 512;
static constexpr int NHW = 1024;
static constexpr int NG  = 32;
static constexpr int CPG = 16;   // channels per group

#define SCALE 0.044194173824159216f  // 512^-0.5
#define LOG2E 1.4426950408889634f

// ---------------- GroupNorm stats: one block per (b,g); x is fp32 ----------------
__global__ __launch_bounds__(256) void gn_stats_k(const float* __restrict__ x,
                                                  float* __restrict__ stats) {
  int bg = blockIdx.x;  // b*NG + g ; group channels are contiguous
  const float* xp = x + (size_t)bg * CPG * NHW;
  float s = 0.f, ss = 0.f;
  for (int i = threadIdx.x * 4; i < CPG * NHW; i += 256 * 4) {
    float4 v = *(const float4*)&xp[i];
    s += v.x + v.y + v.z + v.w;
    ss += v.x * v.x + v.y * v.y + v.z * v.z + v.w * v.w;
  }
#pragma unroll
  for (int off = 1; off < 64; off <<= 1) {
    s  += __shfl_xor(s,  off, 64);
    ss += __shfl_xor(ss, off, 64);
  }
  __shared__ float red[2][4];
  int wv = threadIdx.x >> 6;
  if ((threadIdx.x & 63) == 0) { red[0][wv] = s; red[1][wv] = ss; }
  __syncthreads();
  if (threadIdx.x == 0) {
    float st  = red[0][0] + red[0][1] + red[0][2] + red[0][3];
    float sst = red[1][0] + red[1][1] + red[1][2] + red[1][3];
    float mean = st * (1.f / 16384.f);
    float var  = sst * (1.f / 16384.f) - mean * mean;
    stats[bg * 2]     = mean;
    stats[bg * 2 + 1] = rsqrtf(var + 1e-6f);
  }
}

// ------------- normalize + transpose: hnT[b][n][c] (bf16) <- GN(x[b][c][n]) (fp32) -------------
__global__ __launch_bounds__(256) void gn_apply_k(const float* __restrict__ x,
                                                  const float* __restrict__ gamma,
                                                  const float* __restrict__ beta,
                                                  const float* __restrict__ stats,
                                                  bf16_t* __restrict__ hnT) {
  int bi = blockIdx.z;
  int c0 = blockIdx.y * 32;
  int n0 = blockIdx.x * 32;
  __shared__ float tile[32][33];
  int tn = threadIdx.x & 31;
  int tr = threadIdx.x >> 5;  // 0..7
  const float* xb = x + (size_t)bi * NC * NHW;
#pragma unroll
  for (int r = 0; r < 4; r++) {
    int c = c0 + tr + r * 8;
    int g = c >> 4;
    float mean = stats[(bi * NG + g) * 2];
    float rstd = stats[(bi * NG + g) * 2 + 1];
    float ga = gamma[c], be = beta[c];
    float v = xb[(size_t)c * NHW + n0 + tn];
    tile[tr + r * 8][tn] = (v - mean) * rstd * ga + be;
  }
  __syncthreads();
  bf16_t* hb = hnT + (size_t)bi * NHW * NC;
#pragma unroll
  for (int r = 0; r < 4; r++)
    hb[(size_t)(n0 + tr + r * 8) * NC + c0 + tn] = (bf16_t)tile[tn][tr + r * 8];
}

// ------------- transpose weights: Wt[w][d][c] (bf16) = W_w[c][d] (fp32) -------------
__global__ __launch_bounds__(256) void wtrans_k(const float* __restrict__ W0,
                                                const float* __restrict__ W1,
                                                const float* __restrict__ W2,
                                                const float* __restrict__ W3,
                                                bf16_t* __restrict__ Wt) {
  int w = blockIdx.z;
  const float* W = (w == 0) ? W0 : (w == 1) ? W1 : (w == 2) ? W2 : W3;
  int d0 = blockIdx.x * 32, c0 = blockIdx.y * 32;
  __shared__ float tile[32][33];
  int tdx = threadIdx.x & 31, tr = threadIdx.x >> 5;
#pragma unroll
  for (int r = 0; r < 4; r++)
    tile[tr + r * 8][tdx] = W[(size_t)(c0 + tr + r * 8) * NC + d0 + tdx];
  __syncthreads();
  bf16_t* o = Wt + (size_t)w * NC * NC;
#pragma unroll
  for (int r = 0; r < 4; r++)
    o[(size_t)(d0 + tr + r * 8) * NC + c0 + tdx] = (bf16_t)tile[tdx][tr + r * 8];
}

// ------------- QKV GEMM: out[n][d] = hnT[n][:]·Wt[d][:] + bias[d] -------------
// z = wsel*16 + b ; wsel 0,1 -> Qt/Kt [n][d]; wsel 2 -> V stored transposed [d][n]
__global__ __launch_bounds__(256) void gemm_qkv_k(const bf16_t* __restrict__ hnT,
                                                  const bf16_t* __restrict__ Wt,
                                                  const float* __restrict__ b0,
                                                  const float* __restrict__ b1,
                                                  const float* __restrict__ b2,
                                                  bf16_t* __restrict__ Qt,
                                                  bf16_t* __restrict__ Kt,
                                                  bf16_t* __restrict__ Vm) {
  int bz = blockIdx.z;
  int bi = bz & 15, wsel = bz >> 4;
  int n0 = blockIdx.x * 64;  // over d
  int m0 = blockIdx.y * 64;  // over spatial n
  const bf16_t* A  = hnT + (size_t)bi * NHW * NC;
  const bf16_t* Bm = Wt + (size_t)wsel * NC * NC;
  const float* bias = (wsel == 0) ? b0 : (wsel == 1) ? b1 : b2;

  __shared__ bf16_t As[64][40];
  __shared__ bf16_t Bs[64][40];

  int tid = threadIdx.x;
  int lane = tid & 63, wv = tid >> 6;
  int l16 = lane & 15, quad = lane >> 4;
  int mo = (wv & 1) * 32, no = (wv >> 1) * 32;

  floatx4 zero = {0.f, 0.f, 0.f, 0.f};
  floatx4 acc[2][2];
  acc[0][0] = zero; acc[0][1] = zero; acc[1][0] = zero; acc[1][1] = zero;

  int ldrow = tid >> 2;        // 0..63
  int ldcol = (tid & 3) * 8;   // 0,8,16,24

  for (int k0 = 0; k0 < NC; k0 += 32) {
    *(bf16x8*)&As[ldrow][ldcol] = *(const bf16x8*)&A[(size_t)(m0 + ldrow) * NC + k0 + ldcol];
    *(bf16x8*)&Bs[ldrow][ldcol] = *(const bf16x8*)&Bm[(size_t)(n0 + ldrow) * NC + k0 + ldcol];
    __syncthreads();
    bf16x8 af[2], bfm[2];
#pragma unroll
    for (int i = 0; i < 2; i++) af[i]  = *(bf16x8*)&As[mo + i * 16 + l16][quad * 8];
#pragma unroll
    for (int i = 0; i < 2; i++) bfm[i] = *(bf16x8*)&Bs[no + i * 16 + l16][quad * 8];
#pragma unroll
    for (int mi = 0; mi < 2; mi++)
#pragma unroll
      for (int ni = 0; ni < 2; ni++)
        acc[mi][ni] = __builtin_amdgcn_mfma_f32_16x16x32_bf16(af[mi], bfm[ni], acc[mi][ni], 0, 0, 0);
    __syncthreads();
  }

  size_t obase = (size_t)bi * NHW * NC;
#pragma unroll
  for (int mi = 0; mi < 2; mi++)
#pragma unroll
    for (int ni = 0; ni < 2; ni++) {
      int col = n0 + no + ni * 16 + l16;       // d
      float bv = bias[col];
      int mrow = m0 + mo + mi * 16 + quad * 4; // spatial n base (mult of 4)
      if (wsel < 2) {
        bf16_t* out = ((wsel == 0) ? Qt : Kt) + obase;
#pragma unroll
        for (int r = 0; r < 4; r++)
          out[(size_t)(mrow + r) * NC + col] = (bf16_t)(acc[mi][ni][r] + bv);
      } else {
        bf16x4 pk;
#pragma unroll
        for (int r = 0; r < 4; r++) pk[r] = (bf16_t)(acc[mi][ni][r] + bv);
        *(bf16x4*)&Vm[obase + (size_t)col * NHW + mrow] = pk;
      }
    }
}

// ------------- flash attention: Ot[n][c] -------------
// block = 128 threads = 2 waves, 16 q-rows per wave; grid (32 qblocks, 16 batches)
__global__ __launch_bounds__(128) void attn_k(const bf16_t* __restrict__ Qt,
                                              const bf16_t* __restrict__ Kt,
                                              const bf16_t* __restrict__ Vm,
                                              bf16_t* __restrict__ Ot) {
  int bi = blockIdx.y;
  int tid = threadIdx.x, lane = tid & 63, wv = tid >> 6;
  int l16 = lane & 15, quad = lane >> 4;
  int qrow = blockIdx.x * 32 + wv * 16;
  const bf16_t* Q = Qt + (size_t)bi * NHW * NC;
  const bf16_t* K = Kt + (size_t)bi * NHW * NC;
  const bf16_t* V = Vm + (size_t)bi * NC * NHW;

  __shared__ bf16_t Ks[32][520];    // K-tile [nk_local][d], +8 pad
  __shared__ bf16_t Ps[2][16][40];  // per-wave P strip [m][nk_local], +8 pad

  // preload this wave's Q strip fragments (16 rows x 512)
  bf16x8 qfr[16];
#pragma unroll
  for (int k = 0; k < 16; k++)
    qfr[k] = *(const bf16x8*)&Q[(size_t)(qrow + l16) * NC + k * 32 + quad * 8];

  float m_run[4], l_run[4];
  floatx4 zero = {0.f, 0.f, 0.f, 0.f};
  floatx4 oacc[32];
#pragma unroll
  for (int r = 0; r < 4; r++) { m_run[r] = -1e30f; l_run[r] = 0.f; }
#pragma unroll
  for (int i = 0; i < 32; i++) oacc[i] = zero;

  int srow = tid >> 2;        // 0..31 staging row
  int scch = (tid & 3) * 8;   // staging col base

  for (int t = 0; t < 32; t++) {
    int nk0 = t * 32;
    __syncthreads();  // prior tile fully consumed
    // stage K tile 32x512 (each thread 16x 16B)
#pragma unroll
    for (int i = 0; i < 16; i++)
      *(bf16x8*)&Ks[srow][scch + i * 32] =
          *(const bf16x8*)&K[(size_t)(nk0 + srow) * NC + scch + i * 32];
    __syncthreads();

    // S = Q K^T for this wave's 16 rows x 32 cols
    floatx4 sacc[2];
    sacc[0] = zero; sacc[1] = zero;
#pragma unroll
    for (int k = 0; k < 16; k++) {
#pragma unroll
      for (int ct = 0; ct < 2; ct++) {
        bf16x8 bfr = *(bf16x8*)&Ks[ct * 16 + l16][k * 32 + quad * 8];
        sacc[ct] = __builtin_amdgcn_mfma_f32_16x16x32_bf16(qfr[k], bfr, sacc[ct], 0, 0, 0);
      }
    }
#pragma unroll
    for (int ct = 0; ct < 2; ct++)
#pragma unroll
      for (int r = 0; r < 4; r++) sacc[ct][r] *= SCALE;

    // online softmax (rows = quad*4+r, cols across l16 within quad and ct)
    float alpha[4];
#pragma unroll
    for (int r = 0; r < 4; r++) {
      float mx = fmaxf(sacc[0][r], sacc[1][r]);
#pragma unroll
      for (int off = 1; off < 16; off <<= 1) mx = fmaxf(mx, __shfl_xor(mx, off, 64));
      float mnew = fmaxf(m_run[r], mx);
      alpha[r] = exp2f((m_run[r] - mnew) * LOG2E);
      m_run[r] = mnew;
      float rs = 0.f;
#pragma unroll
      for (int ct = 0; ct < 2; ct++) {
        float p = exp2f((sacc[ct][r] - mnew) * LOG2E);
        sacc[ct][r] = p;
        rs += p;
      }
#pragma unroll
      for (int off = 1; off < 16; off <<= 1) rs += __shfl_xor(rs, off, 64);
      l_run[r] = l_run[r] * alpha[r] + rs;
    }

    // write P (C-layout -> row-major [m][nk])
#pragma unroll
    for (int ct = 0; ct < 2; ct++)
#pragma unroll
      for (int r = 0; r < 4; r++)
        Ps[wv][quad * 4 + r][ct * 16 + l16] = (bf16_t)sacc[ct][r];

    // rescale O
#pragma unroll
    for (int i = 0; i < 32; i++)
#pragma unroll
      for (int r = 0; r < 4; r++) oacc[i][r] *= alpha[r];

    __syncthreads();  // P write -> read visibility

    // O += P V^T : A = P [16x32], B[k=nk][n=c] from V[c][nk]
    bf16x8 pfr = *(bf16x8*)&Ps[wv][l16][quad * 8];
#pragma unroll
    for (int ct2 = 0; ct2 < 32; ct2++) {
      bf16x8 vfr = *(const bf16x8*)&V[(size_t)(ct2 * 16 + l16) * NHW + nk0 + quad * 8];
      oacc[ct2] = __builtin_amdgcn_mfma_f32_16x16x32_bf16(pfr, vfr, oacc[ct2], 0, 0, 0);
    }
  }

  bf16_t* Ob = Ot + (size_t)bi * NHW * NC;
  float inv[4];
#pragma unroll
  for (int r = 0; r < 4; r++) inv[r] = 1.f / l_run[r];
#pragma unroll
  for (int ct2 = 0; ct2 < 32; ct2++)
#pragma unroll
    for (int r = 0; r < 4; r++)
      Ob[(size_t)(qrow + quad * 4 + r) * NC + ct2 * 16 + l16] = (bf16_t)(oacc[ct2][r] * inv[r]);
}

// ------------- final GEMM + bias + residual: out[d][n] (fp32) = Ot[n][:]·W3t[d][:] + b3[d] + x[d][n] -------------
__global__ __launch_bounds__(256) void gemm_final_k(const bf16_t* __restrict__ Ot,
                                                    const bf16_t* __restrict__ W3t,
                                                    const float* __restrict__ b3,
                                                    const float* __restrict__ x,
                                                    float* __restrict__ outp) {
  int bi = blockIdx.z;
  int n0 = blockIdx.x * 64;  // over d
  int m0 = blockIdx.y * 64;  // over spatial n
  const bf16_t* A = Ot + (size_t)bi * NHW * NC;

  __shared__ bf16_t As[64][40];
  __shared__ bf16_t Bs[64][40];

  int tid = threadIdx.x;
  int lane = tid & 63, wv = tid >> 6;
  int l16 = lane & 15, quad = lane >> 4;
  int mo = (wv & 1) * 32, no = (wv >> 1) * 32;

  floatx4 zero = {0.f, 0.f, 0.f, 0.f};
  floatx4 acc[2][2];
  acc[0][0] = zero; acc[0][1] = zero; acc[1][0] = zero; acc[1][1] = zero;

  int ldrow = tid >> 2;
  int ldcol = (tid & 3) * 8;

  for (int k0 = 0; k0 < NC; k0 += 32) {
    *(bf16x8*)&As[ldrow][ldcol] = *(const bf16x8*)&A[(size_t)(m0 + ldrow) * NC + k0 + ldcol];
    *(bf16x8*)&Bs[ldrow][ldcol] = *(const bf16x8*)&W3t[(size_t)(n0 + ldrow) * NC + k0 + ldcol];
    __syncthreads();
    bf16x8 af[2], bfm[2];
#pragma unroll
    for (int i = 0; i < 2; i++) af[i]  = *(bf16x8*)&As[mo + i * 16 + l16][quad * 8];
#pragma unroll
    for (int i = 0; i < 2; i++) bfm[i] = *(bf16x8*)&Bs[no + i * 16 + l16][quad * 8];
#pragma unroll
    for (int mi = 0; mi < 2; mi++)
#pragma unroll
      for (int ni = 0; ni < 2; ni++)
        acc[mi][ni] = __builtin_amdgcn_mfma_f32_16x16x32_bf16(af[mi], bfm[ni], acc[mi][ni], 0, 0, 0);
    __syncthreads();
  }

  const float* xb = x + (size_t)bi * NC * NHW;
  float* ob = outp + (size_t)bi * NC * NHW;
#pragma unroll
  for (int mi = 0; mi < 2; mi++)
#pragma unroll
    for (int ni = 0; ni < 2; ni++) {
      int col = n0 + no + ni * 16 + l16;        // d
      float bv = b3[col];
      int mrow = m0 + mo + mi * 16 + quad * 4;  // spatial n base
      size_t base = (size_t)col * NHW + mrow;
      float4 xv = *(const float4*)&xb[base];
      float4 pk;
      pk.x = acc[mi][ni][0] + bv + xv.x;
      pk.y = acc[mi][ni][1] + bv + xv.y;
      pk.z = acc[mi][ni][2] + bv + xv.z;
      pk.w = acc[mi][ni][3] + bv + xv.w;
      *(float4*)&ob[base] = pk;
    }
}

extern "C" void kernel_launch(void* const* d_in, const int* in_sizes, int n_in,
                              void* d_out, int out_size, void* d_ws, size_t ws_size,
                              hipStream_t stream) {
  (void)in_sizes; (void)n_in; (void)out_size; (void)ws_size;
  const float* x     = (const float*)d_in[0];
  const float* gamma = (const float*)d_in[1];
  const float* beta  = (const float*)d_in[2];
  const float* W0    = (const float*)d_in[3];
  const float* b0    = (const float*)d_in[4];
  const float* W1    = (const float*)d_in[5];
  const float* b1    = (const float*)d_in[6];
  const float* W2    = (const float*)d_in[7];
  const float* b2    = (const float*)d_in[8];
  const float* W3    = (const float*)d_in[9];
  const float* b3    = (const float*)d_in[10];
  float* outp = (float*)d_out;

  char* ws = (char*)d_ws;
  const size_t PLANE = (size_t)NB * NHW * NC * sizeof(bf16_t);  // 16 MB
  float* stats = (float*)ws;
  size_t off = 4096;
  bf16_t* hnT = (bf16_t*)(ws + off);            // also reused as Ot after QKV
  off += PLANE;
  bf16_t* Qt = (bf16_t*)(ws + off); off += PLANE;
  bf16_t* Kt = (bf16_t*)(ws + off); off += PLANE;
  bf16_t* Vm = (bf16_t*)(ws + off); off += PLANE;
  bf16_t* Wt = (bf16_t*)(ws + off); off += 4 * (size_t)NC * NC * sizeof(bf16_t);
  bf16_t* Ot = hnT;  // hnT dead after gemm_qkv

  gn_stats_k<<<NB * NG, 256, 0, stream>>>(x, stats);
  gn_apply_k<<<dim3(32, 16, NB), 256, 0, stream>>>(x, gamma, beta, stats, hnT);
  wtrans_k<<<dim3(16, 16, 4), 256, 0, stream>>>(W0, W1, W2, W3, Wt);
  gemm_qkv_k<<<dim3(8, 16, 48), 256, 0, stream>>>(hnT, Wt, b0, b1, b2, Qt, Kt, Vm);
  attn_k<<<dim3(32, NB), 128, 0, stream>>>(Qt, Kt, Vm, Ot);
  gemm_final_k<<<dim3(8, 16, NB), 256, 0, stream>>>(Ot, Wt + 3 * (size_t)NC * NC, b3, x, outp);
}

// Round 4
// 259.572 us; speedup vs baseline: 2.3642x; 2.3642x over previous
//
#include <hip/hip_runtime.h>
#include <stdint.h>

typedef __bf16 bf16_t;
typedef _Float16 f16_t;
typedef bf16_t bf16x8 __attribute__((ext_vector_type(8)));
typedef bf16_t bf16x4 __attribute__((ext_vector_type(4)));
typedef f16_t  f16x8  __attribute__((ext_vector_type(8)));
typedef float floatx4 __attribute__((ext_vector_type(4)));

static constexpr int NB  = 16;
static constexpr int NC  = 512;
static constexpr int NHW = 1024;
static constexpr int NG  = 32;
static constexpr int CPG = 16;   // channels per group

#define SCALE 0.044194173824159216f  // 512^-0.5
#define LOG2E 1.4426950408889634f

// ---------------- GroupNorm stats: one block per (b,g); x is fp32 ----------------
__global__ __launch_bounds__(256) void gn_stats_k(const float* __restrict__ x,
                                                  float* __restrict__ stats) {
  int bg = blockIdx.x;
  const float* xp = x + (size_t)bg * CPG * NHW;
  float s = 0.f, ss = 0.f;
  for (int i = threadIdx.x * 4; i < CPG * NHW; i += 256 * 4) {
    float4 v = *(const float4*)&xp[i];
    s += v.x + v.y + v.z + v.w;
    ss += v.x * v.x + v.y * v.y + v.z * v.z + v.w * v.w;
  }
#pragma unroll
  for (int off = 1; off < 64; off <<= 1) {
    s  += __shfl_xor(s,  off, 64);
    ss += __shfl_xor(ss, off, 64);
  }
  __shared__ float red[2][4];
  int wv = threadIdx.x >> 6;
  if ((threadIdx.x & 63) == 0) { red[0][wv] = s; red[1][wv] = ss; }
  __syncthreads();
  if (threadIdx.x == 0) {
    float st  = red[0][0] + red[0][1] + red[0][2] + red[0][3];
    float sst = red[1][0] + red[1][1] + red[1][2] + red[1][3];
    float mean = st * (1.f / 16384.f);
    float var  = sst * (1.f / 16384.f) - mean * mean;
    stats[bg * 2]     = mean;
    stats[bg * 2 + 1] = rsqrtf(var + 1e-6f);
  }
}

// ------------- normalize + transpose: hnT[b][n][c] (bf16) <- GN(x[b][c][n]) (fp32) -------------
__global__ __launch_bounds__(256) void gn_apply_k(const float* __restrict__ x,
                                                  const float* __restrict__ gamma,
                                                  const float* __restrict__ beta,
                                                  const float* __restrict__ stats,
                                                  bf16_t* __restrict__ hnT) {
  int bi = blockIdx.z;
  int c0 = blockIdx.y * 32;
  int n0 = blockIdx.x * 32;
  __shared__ float tile[32][33];
  int tn = threadIdx.x & 31;
  int tr = threadIdx.x >> 5;  // 0..7
  const float* xb = x + (size_t)bi * NC * NHW;
#pragma unroll
  for (int r = 0; r < 4; r++) {
    int c = c0 + tr + r * 8;
    int g = c >> 4;
    float mean = stats[(bi * NG + g) * 2];
    float rstd = stats[(bi * NG + g) * 2 + 1];
    float ga = gamma[c], be = beta[c];
    float v = xb[(size_t)c * NHW + n0 + tn];
    tile[tr + r * 8][tn] = (v - mean) * rstd * ga + be;
  }
  __syncthreads();
  bf16_t* hb = hnT + (size_t)bi * NHW * NC;
#pragma unroll
  for (int r = 0; r < 4; r++)
    hb[(size_t)(n0 + tr + r * 8) * NC + c0 + tn] = (bf16_t)tile[tn][tr + r * 8];
}

// ------------- transpose weights: Wt[w][d][c] (bf16) = W_w[c][d] (fp32) -------------
__global__ __launch_bounds__(256) void wtrans_k(const float* __restrict__ W0,
                                                const float* __restrict__ W1,
                                                const float* __restrict__ W2,
                                                const float* __restrict__ W3,
                                                bf16_t* __restrict__ Wt) {
  int w = blockIdx.z;
  const float* W = (w == 0) ? W0 : (w == 1) ? W1 : (w == 2) ? W2 : W3;
  int d0 = blockIdx.x * 32, c0 = blockIdx.y * 32;
  __shared__ float tile[32][33];
  int tdx = threadIdx.x & 31, tr = threadIdx.x >> 5;
#pragma unroll
  for (int r = 0; r < 4; r++)
    tile[tr + r * 8][tdx] = W[(size_t)(c0 + tr + r * 8) * NC + d0 + tdx];
  __syncthreads();
  bf16_t* o = Wt + (size_t)w * NC * NC;
#pragma unroll
  for (int r = 0; r < 4; r++)
    o[(size_t)(d0 + tr + r * 8) * NC + c0 + tdx] = (bf16_t)tile[tdx][tr + r * 8];
}

// ---------------- async global->LDS, 16B per lane ----------------
__device__ __forceinline__ void glds16(const bf16_t* g, bf16_t* lds) {
  __builtin_amdgcn_global_load_lds(
      (const __attribute__((address_space(1))) unsigned int*)g,
      (__attribute__((address_space(3))) unsigned int*)lds, 16, 0, 0);
}

// ---------------- 128x128x32 MFMA GEMM core (m97-style) ----------------
// A [M][KDIM], B [N][KDIM] row-major bf16 (NT). acc[i][j]: 16x16 tile at
// rows m0+wm*64+i*16, cols n0+wn*64+j*16. LDS unpadded: row = 64B, staged by
// global_load_lds (lane l -> base + l*16: rows of 64B in lane order).
template<int KDIM>
__device__ __forceinline__ void gemm_core128(const bf16_t* __restrict__ A,
                                             const bf16_t* __restrict__ B,
                                             int m0, int n0,
                                             floatx4 (&acc)[4][4]) {
  __shared__ bf16_t As[128 * 32];
  __shared__ bf16_t Bs[128 * 32];
  const int tid = threadIdx.x, lane = tid & 63, wv = tid >> 6;
  const int l16 = lane & 15, quad = lane >> 4;
  const int wm = wv & 1, wn = wv >> 1;

  // wave wv stages rows [wv*32, wv*32+32) of each tile, 2 insts x 16 rows
  const bf16_t* aptr = A + (size_t)(m0 + wv * 32 + (lane >> 2)) * KDIM + (lane & 3) * 8;
  const bf16_t* bptr = B + (size_t)(n0 + wv * 32 + (lane >> 2)) * KDIM + (lane & 3) * 8;
  bf16_t* as0 = &As[(wv * 32) * 32];
  bf16_t* as1 = &As[(wv * 32 + 16) * 32];
  bf16_t* bs0 = &Bs[(wv * 32) * 32];
  bf16_t* bs1 = &Bs[(wv * 32 + 16) * 32];

  for (int k0 = 0; k0 < KDIM; k0 += 32) {
    __syncthreads();                      // prior tile consumed
    glds16(aptr, as0);
    glds16(aptr + (size_t)16 * KDIM, as1);
    glds16(bptr, bs0);
    glds16(bptr + (size_t)16 * KDIM, bs1);
    aptr += 32; bptr += 32;
    __syncthreads();                      // glds drained (vmcnt before barrier)
    bf16x8 af[4], bfv[4];
#pragma unroll
    for (int i = 0; i < 4; i++)
      af[i] = *(const bf16x8*)&As[(wm * 64 + i * 16 + l16) * 32 + quad * 8];
#pragma unroll
    for (int j = 0; j < 4; j++)
      bfv[j] = *(const bf16x8*)&Bs[(wn * 64 + j * 16 + l16) * 32 + quad * 8];
#pragma unroll
    for (int i = 0; i < 4; i++)
#pragma unroll
      for (int j = 0; j < 4; j++)
        acc[i][j] = __builtin_amdgcn_mfma_f32_16x16x32_bf16(af[i], bfv[j], acc[i][j], 0, 0, 0);
  }
}

// ------------- QKV GEMM: z = wsel*16+b; Qt/Kt [n][d], Vm [d][n] -------------
__global__ __launch_bounds__(256) void gemm_qkv2_k(const bf16_t* __restrict__ hnT,
                                                   const bf16_t* __restrict__ Wt,
                                                   const float* __restrict__ b0,
                                                   const float* __restrict__ b1,
                                                   const float* __restrict__ b2,
                                                   bf16_t* __restrict__ Qt,
                                                   bf16_t* __restrict__ Kt,
                                                   bf16_t* __restrict__ Vm) {
  int bz = blockIdx.z, bi = bz & 15, wsel = bz >> 4;
  int n0 = blockIdx.x * 128, m0 = blockIdx.y * 128;
  const bf16_t* A = hnT + (size_t)bi * NHW * NC;
  const bf16_t* B = Wt + (size_t)wsel * NC * NC;
  floatx4 acc[4][4];
#pragma unroll
  for (int i = 0; i < 4; i++)
#pragma unroll
    for (int j = 0; j < 4; j++) acc[i][j] = (floatx4){0.f, 0.f, 0.f, 0.f};
  gemm_core128<NC>(A, B, m0, n0, acc);

  const int lane = threadIdx.x & 63, wv = threadIdx.x >> 6;
  const int l16 = lane & 15, quad = lane >> 4, wm = wv & 1, wn = wv >> 1;
  const float* bias = (wsel == 0) ? b0 : (wsel == 1) ? b1 : b2;
  if (wsel < 2) {
    bf16_t* out = ((wsel == 0) ? Qt : Kt) + (size_t)bi * NHW * NC;
#pragma unroll
    for (int i = 0; i < 4; i++)
#pragma unroll
      for (int j = 0; j < 4; j++) {
        int row = m0 + wm * 64 + i * 16 + quad * 4;
        int col = n0 + wn * 64 + j * 16 + l16;
        float bv = bias[col];
#pragma unroll
        for (int r = 0; r < 4; r++)
          out[(size_t)(row + r) * NC + col] = (bf16_t)(acc[i][j][r] + bv);
      }
  } else {
    bf16_t* out = Vm + (size_t)bi * NC * NHW;
#pragma unroll
    for (int i = 0; i < 4; i++)
#pragma unroll
      for (int j = 0; j < 4; j++) {
        int row = m0 + wm * 64 + i * 16 + quad * 4;
        int col = n0 + wn * 64 + j * 16 + l16;
        float bv = bias[col];
        bf16x4 pk;
#pragma unroll
        for (int r = 0; r < 4; r++) pk[r] = (bf16_t)(acc[i][j][r] + bv);
        *(bf16x4*)&out[(size_t)col * NHW + row] = pk;
      }
  }
}

// ------------- S GEMM: S[b][i][j] (fp16) = SCALE * Qt[i][:]·Kt[j][:] -------------
__global__ __launch_bounds__(256) void gemm_s_k(const bf16_t* __restrict__ Qt,
                                                const bf16_t* __restrict__ Kt,
                                                f16_t* __restrict__ S) {
  int bi = blockIdx.z;
  int n0 = blockIdx.x * 128, m0 = blockIdx.y * 128;
  const bf16_t* A = Qt + (size_t)bi * NHW * NC;
  const bf16_t* B = Kt + (size_t)bi * NHW * NC;
  floatx4 acc[4][4];
#pragma unroll
  for (int i = 0; i < 4; i++)
#pragma unroll
    for (int j = 0; j < 4; j++) acc[i][j] = (floatx4){0.f, 0.f, 0.f, 0.f};
  gemm_core128<NC>(A, B, m0, n0, acc);

  const int lane = threadIdx.x & 63, wv = threadIdx.x >> 6;
  const int l16 = lane & 15, quad = lane >> 4, wm = wv & 1, wn = wv >> 1;
  f16_t* out = S + (size_t)bi * NHW * NHW;
#pragma unroll
  for (int i = 0; i < 4; i++)
#pragma unroll
    for (int j = 0; j < 4; j++) {
      int row = m0 + wm * 64 + i * 16 + quad * 4;
      int col = n0 + wn * 64 + j * 16 + l16;
#pragma unroll
      for (int r = 0; r < 4; r++)
        out[(size_t)(row + r) * NHW + col] = (f16_t)(acc[i][j][r] * SCALE);
    }
}

// ------------- softmax: one wave per row of 1024; P (bf16) overwrites S (fp16) in place -------------
__global__ __launch_bounds__(256) void softmax_k(const f16_t* __restrict__ S,
                                                 bf16_t* __restrict__ P) {
  int row = blockIdx.x * 4 + (threadIdx.x >> 6);   // 0..16383 (b folded)
  int lane = threadIdx.x & 63;
  const f16_t* sp = S + (size_t)row * NHW + lane * 16;
  f16x8 a = *(const f16x8*)sp;
  f16x8 b = *(const f16x8*)(sp + 8);
  float v[16];
#pragma unroll
  for (int k = 0; k < 8; k++) { v[k] = (float)a[k]; v[8 + k] = (float)b[k]; }
  float mx = v[0];
#pragma unroll
  for (int k = 1; k < 16; k++) mx = fmaxf(mx, v[k]);
#pragma unroll
  for (int off = 1; off < 64; off <<= 1) mx = fmaxf(mx, __shfl_xor(mx, off, 64));
  float e[16], s = 0.f;
#pragma unroll
  for (int k = 0; k < 16; k++) { e[k] = exp2f((v[k] - mx) * LOG2E); s += e[k]; }
#pragma unroll
  for (int off = 1; off < 64; off <<= 1) s += __shfl_xor(s, off, 64);
  float inv = 1.f / s;
  bf16x8 o0, o1;
#pragma unroll
  for (int k = 0; k < 8; k++) { o0[k] = (bf16_t)(e[k] * inv); o1[k] = (bf16_t)(e[8 + k] * inv); }
  bf16_t* pp = P + (size_t)row * NHW + lane * 16;
  *(bf16x8*)pp = o0;
  *(bf16x8*)(pp + 8) = o1;
}

// ------------- PV GEMM: Ot[i][c] (bf16) = P[i][:]·Vm[c][:] (K=1024) -------------
__global__ __launch_bounds__(256) void gemm_pv_k(const bf16_t* __restrict__ P,
                                                 const bf16_t* __restrict__ Vm,
                                                 bf16_t* __restrict__ Ot) {
  int bi = blockIdx.z;
  int n0 = blockIdx.x * 128, m0 = blockIdx.y * 128;
  const bf16_t* A = P + (size_t)bi * NHW * NHW;
  const bf16_t* B = Vm + (size_t)bi * NC * NHW;
  floatx4 acc[4][4];
#pragma unroll
  for (int i = 0; i < 4; i++)
#pragma unroll
    for (int j = 0; j < 4; j++) acc[i][j] = (floatx4){0.f, 0.f, 0.f, 0.f};
  gemm_core128<NHW>(A, B, m0, n0, acc);

  const int lane = threadIdx.x & 63, wv = threadIdx.x >> 6;
  const int l16 = lane & 15, quad = lane >> 4, wm = wv & 1, wn = wv >> 1;
  bf16_t* out = Ot + (size_t)bi * NHW * NC;
#pragma unroll
  for (int i = 0; i < 4; i++)
#pragma unroll
    for (int j = 0; j < 4; j++) {
      int row = m0 + wm * 64 + i * 16 + quad * 4;
      int col = n0 + wn * 64 + j * 16 + l16;
#pragma unroll
      for (int r = 0; r < 4; r++)
        out[(size_t)(row + r) * NC + col] = (bf16_t)(acc[i][j][r]);
    }
}

// ------------- final GEMM + bias + residual: out[d][n] (fp32) -------------
__global__ __launch_bounds__(256) void gemm_fin_k(const bf16_t* __restrict__ Ot,
                                                  const bf16_t* __restrict__ W3t,
                                                  const float* __restrict__ b3,
                                                  const float* __restrict__ x,
                                                  float* __restrict__ outp) {
  int bi = blockIdx.z;
  int n0 = blockIdx.x * 128, m0 = blockIdx.y * 128;
  const bf16_t* A = Ot + (size_t)bi * NHW * NC;
  floatx4 acc[4][4];
#pragma unroll
  for (int i = 0; i < 4; i++)
#pragma unroll
    for (int j = 0; j < 4; j++) acc[i][j] = (floatx4){0.f, 0.f, 0.f, 0.f};
  gemm_core128<NC>(A, W3t, m0, n0, acc);

  const int lane = threadIdx.x & 63, wv = threadIdx.x >> 6;
  const int l16 = lane & 15, quad = lane >> 4, wm = wv & 1, wn = wv >> 1;
  const float* xb = x + (size_t)bi * NC * NHW;
  float* ob = outp + (size_t)bi * NC * NHW;
#pragma unroll
  for (int i = 0; i < 4; i++)
#pragma unroll
    for (int j = 0; j < 4; j++) {
      int row = m0 + wm * 64 + i * 16 + quad * 4;  // spatial n
      int col = n0 + wn * 64 + j * 16 + l16;       // channel d
      float bv = b3[col];
      size_t base = (size_t)col * NHW + row;
      float4 xv = *(const float4*)&xb[base];
      float4 pk;
      pk.x = acc[i][j][0] + bv + xv.x;
      pk.y = acc[i][j][1] + bv + xv.y;
      pk.z = acc[i][j][2] + bv + xv.z;
      pk.w = acc[i][j][3] + bv + xv.w;
      *(float4*)&ob[base] = pk;
    }
}

extern "C" void kernel_launch(void* const* d_in, const int* in_sizes, int n_in,
                              void* d_out, int out_size, void* d_ws, size_t ws_size,
                              hipStream_t stream) {
  (void)in_sizes; (void)n_in; (void)out_size; (void)ws_size;
  const float* x     = (const float*)d_in[0];
  const float* gamma = (const float*)d_in[1];
  const float* beta  = (const float*)d_in[2];
  const float* W0    = (const float*)d_in[3];
  const float* b0    = (const float*)d_in[4];
  const float* W1    = (const float*)d_in[5];
  const float* b1    = (const float*)d_in[6];
  const float* W2    = (const float*)d_in[7];
  const float* b2    = (const float*)d_in[8];
  const float* W3    = (const float*)d_in[9];
  const float* b3    = (const float*)d_in[10];
  float* outp = (float*)d_out;

  char* ws = (char*)d_ws;
  const size_t PLANE = (size_t)NB * NHW * NC * sizeof(bf16_t);  // 16 MB
  float* stats = (float*)ws;
  size_t off = 4096;
  bf16_t* hnT = (bf16_t*)(ws + off); off += PLANE;   // reused as Ot after PV
  bf16_t* Qt  = (bf16_t*)(ws + off); off += PLANE;
  bf16_t* Kt  = (bf16_t*)(ws + off); off += PLANE;
  bf16_t* Vm  = (bf16_t*)(ws + off); off += PLANE;
  bf16_t* Wt  = (bf16_t*)(ws + off); off += 4 * (size_t)NC * NC * sizeof(bf16_t);
  f16_t*  S   = (f16_t*)(ws + off);  off += (size_t)NB * NHW * NHW * sizeof(f16_t);  // 32 MB
  bf16_t* P   = (bf16_t*)S;  // softmax writes bf16 in place
  bf16_t* Ot  = hnT;         // hnT dead after gemm_qkv2

  gn_stats_k<<<NB * NG, 256, 0, stream>>>(x, stats);
  gn_apply_k<<<dim3(32, 16, NB), 256, 0, stream>>>(x, gamma, beta, stats, hnT);
  wtrans_k<<<dim3(16, 16, 4), 256, 0, stream>>>(W0, W1, W2, W3, Wt);
  gemm_qkv2_k<<<dim3(4, 8, 48), 256, 0, stream>>>(hnT, Wt, b0, b1, b2, Qt, Kt, Vm);
  gemm_s_k<<<dim3(8, 8, NB), 256, 0, stream>>>(Qt, Kt, S);
  softmax_k<<<dim3(NB * NHW / 4), 256, 0, stream>>>(S, P);
  gemm_pv_k<<<dim3(4, 8, NB), 256, 0, stream>>>(P, Vm, Ot);
  gemm_fin_k<<<dim3(4, 8, NB), 256, 0, stream>>>(Ot, Wt + 3 * (size_t)NC * NC, b3, x, outp);
}

// Round 5
// 257.851 us; speedup vs baseline: 2.3800x; 1.0067x over previous
//
#include <hip/hip_runtime.h>
#include <stdint.h>

typedef __bf16 bf16_t;
typedef _Float16 f16_t;
typedef bf16_t bf16x8 __attribute__((ext_vector_type(8)));
typedef bf16_t bf16x4 __attribute__((ext_vector_type(4)));
typedef f16_t  f16x8  __attribute__((ext_vector_type(8)));
typedef f16_t  f16x4  __attribute__((ext_vector_type(4)));
typedef float floatx4 __attribute__((ext_vector_type(4)));

static constexpr int NB  = 16;
static constexpr int NC  = 512;
static constexpr int NHW = 1024;
static constexpr int NG  = 32;
static constexpr int CPG = 16;

#define SCALE 0.044194173824159216f  // 512^-0.5
#define LOG2E 1.4426950408889634f

// ---------------- GroupNorm stats ----------------
__global__ __launch_bounds__(256) void gn_stats_k(const float* __restrict__ x,
                                                  float* __restrict__ stats) {
  int bg = blockIdx.x;
  const float* xp = x + (size_t)bg * CPG * NHW;
  float s = 0.f, ss = 0.f;
  for (int i = threadIdx.x * 4; i < CPG * NHW; i += 256 * 4) {
    float4 v = *(const float4*)&xp[i];
    s += v.x + v.y + v.z + v.w;
    ss += v.x * v.x + v.y * v.y + v.z * v.z + v.w * v.w;
  }
#pragma unroll
  for (int off = 1; off < 64; off <<= 1) {
    s  += __shfl_xor(s,  off, 64);
    ss += __shfl_xor(ss, off, 64);
  }
  __shared__ float red[2][4];
  int wv = threadIdx.x >> 6;
  if ((threadIdx.x & 63) == 0) { red[0][wv] = s; red[1][wv] = ss; }
  __syncthreads();
  if (threadIdx.x == 0) {
    float st  = red[0][0] + red[0][1] + red[0][2] + red[0][3];
    float sst = red[1][0] + red[1][1] + red[1][2] + red[1][3];
    float mean = st * (1.f / 16384.f);
    float var  = sst * (1.f / 16384.f) - mean * mean;
    stats[bg * 2]     = mean;
    stats[bg * 2 + 1] = rsqrtf(var + 1e-6f);
  }
}

// ------------- normalize + transpose: hnT[b][n][c] (bf16), packed 8B stores -------------
__global__ __launch_bounds__(256) void gn_apply_k(const float* __restrict__ x,
                                                  const float* __restrict__ gamma,
                                                  const float* __restrict__ beta,
                                                  const float* __restrict__ stats,
                                                  bf16_t* __restrict__ hnT) {
  int bi = blockIdx.z;
  int c0 = blockIdx.y * 32;
  int n0 = blockIdx.x * 32;
  __shared__ float tile[32][33];
  int tn = threadIdx.x & 31;
  int tr = threadIdx.x >> 5;  // 0..7
  const float* xb = x + (size_t)bi * NC * NHW;
#pragma unroll
  for (int r = 0; r < 4; r++) {
    int c = c0 + tr + r * 8;
    int g = c >> 4;
    float mean = stats[(bi * NG + g) * 2];
    float rstd = stats[(bi * NG + g) * 2 + 1];
    float ga = gamma[c], be = beta[c];
    float v = xb[(size_t)c * NHW + n0 + tn];
    tile[tr + r * 8][tn] = (v - mean) * rstd * ga + be;
  }
  __syncthreads();
  // write: thread t -> row n0+(t>>3), cols c0+(t&7)*4 .. +3, one 8B store
  bf16_t* hb = hnT + (size_t)bi * NHW * NC;
  int nl = threadIdx.x >> 3, cc = (threadIdx.x & 7) * 4;
  bf16x4 pk;
#pragma unroll
  for (int i = 0; i < 4; i++) pk[i] = (bf16_t)tile[cc + i][nl];
  *(bf16x4*)&hb[(size_t)(n0 + nl) * NC + c0 + cc] = pk;
}

// ------------- transpose weights: Wt[w][d][c] (bf16), packed stores -------------
__global__ __launch_bounds__(256) void wtrans_k(const float* __restrict__ W0,
                                                const float* __restrict__ W1,
                                                const float* __restrict__ W2,
                                                const float* __restrict__ W3,
                                                bf16_t* __restrict__ Wt) {
  int w = blockIdx.z;
  const float* W = (w == 0) ? W0 : (w == 1) ? W1 : (w == 2) ? W2 : W3;
  int d0 = blockIdx.x * 32, c0 = blockIdx.y * 32;
  __shared__ float tile[32][33];  // [c_local][d_local]
  int tdx = threadIdx.x & 31, tr = threadIdx.x >> 5;
#pragma unroll
  for (int r = 0; r < 4; r++)
    tile[tr + r * 8][tdx] = W[(size_t)(c0 + tr + r * 8) * NC + d0 + tdx];
  __syncthreads();
  bf16_t* o = Wt + (size_t)w * NC * NC;
  int dl = threadIdx.x >> 3, cc = (threadIdx.x & 7) * 4;
  bf16x4 pk;
#pragma unroll
  for (int i = 0; i < 4; i++) pk[i] = (bf16_t)tile[cc + i][dl];
  *(bf16x4*)&o[(size_t)(d0 + dl) * NC + c0 + cc] = pk;
}

// ---------------- async global->LDS, 16B per lane ----------------
__device__ __forceinline__ void glds16(const bf16_t* g, bf16_t* lds) {
  __builtin_amdgcn_global_load_lds(
      (const __attribute__((address_space(1))) unsigned int*)g,
      (__attribute__((address_space(3))) unsigned int*)lds, 16, 0, 0);
}

__device__ __forceinline__ floatx4 mfma_bf16(bf16x8 a, bf16x8 b, floatx4 c) {
  return __builtin_amdgcn_mfma_f32_16x16x32_bf16(a, b, c, 0, 0, 0);
}

// ---------------- 128x128xBK=64 MFMA GEMM core, XOR-swizzled LDS ----------------
// A [M][KDIM], B [N][KDIM] row-major bf16 (NT form).
// LDS row = 64 bf16 = 8 chunks of 16B; data chunk c of row r stored at slot c^(r&7)
// (swizzle applied on the GLOBAL address during staging -> glds stays legal).
// SWAP=false: acc[i][j] C-tile rows (m) quad*4+r, cols (n) l16.
// SWAP=true : operands swapped -> acc[i][j] holds C^T: "rows" = n (quad*4+r), "cols" = m (l16).
template<int KDIM, bool SWAP>
__device__ __forceinline__ void gemm_core(const bf16_t* __restrict__ A,
                                          const bf16_t* __restrict__ B,
                                          int m0, int n0,
                                          floatx4 (&acc)[4][4]) {
  __shared__ bf16_t As[128 * 64];
  __shared__ bf16_t Bs[128 * 64];
  const int tid = threadIdx.x, lane = tid & 63, wv = tid >> 6;
  const int l16 = lane & 15, quad = lane >> 4;
  const int wm = wv & 1, wn = wv >> 1;
  const int x7 = l16 & 7;

  const int srow = lane >> 3;               // 0..7
  const int schunk = (lane & 7) ^ srow;     // swizzled global chunk
  const bf16_t* aptr = A + (size_t)(m0 + wv * 32 + srow) * KDIM + schunk * 8;
  const bf16_t* bptr = B + (size_t)(n0 + wv * 32 + srow) * KDIM + schunk * 8;
  bf16_t* as_ = &As[(wv * 32) * 64];
  bf16_t* bs_ = &Bs[(wv * 32) * 64];

  for (int k0 = 0; k0 < KDIM; k0 += 64) {
    __syncthreads();                        // prior tile consumed
#pragma unroll
    for (int i = 0; i < 4; i++) {
      glds16(aptr + (size_t)(8 * i) * KDIM, as_ + (8 * i) * 64);
      glds16(bptr + (size_t)(8 * i) * KDIM, bs_ + (8 * i) * 64);
    }
    aptr += 64; bptr += 64;
    __syncthreads();                        // glds drained
    bf16x8 af[2][4], bfv[2][4];
#pragma unroll
    for (int h = 0; h < 2; h++)
#pragma unroll
      for (int i = 0; i < 4; i++) {
        int q = h * 4 + quad;
        af[h][i]  = *(const bf16x8*)&As[(wm * 64 + i * 16 + l16) * 64 + ((q ^ x7) * 8)];
        bfv[h][i] = *(const bf16x8*)&Bs[(wn * 64 + i * 16 + l16) * 64 + ((q ^ x7) * 8)];
      }
#pragma unroll
    for (int h = 0; h < 2; h++)
#pragma unroll
      for (int i = 0; i < 4; i++)
#pragma unroll
        for (int j = 0; j < 4; j++)
          acc[i][j] = SWAP ? mfma_bf16(bfv[h][j], af[h][i], acc[i][j])
                           : mfma_bf16(af[h][i], bfv[h][j], acc[i][j]);
  }
}

#define ACC_INIT(acc)                                   \
  floatx4 acc[4][4];                                    \
  _Pragma("unroll") for (int i = 0; i < 4; i++)         \
  _Pragma("unroll") for (int j = 0; j < 4; j++)         \
    acc[i][j] = (floatx4){0.f, 0.f, 0.f, 0.f};

// ------------- Q/K GEMM (SWAP): out[n][d] = hnT[n][:]·Wt[d][:] + bias, packed 8B stores -------------
__global__ __launch_bounds__(256) void gemm_qk_k(const bf16_t* __restrict__ hnT,
                                                 const bf16_t* __restrict__ Wt,
                                                 const float* __restrict__ b0,
                                                 const float* __restrict__ b1,
                                                 bf16_t* __restrict__ Qt,
                                                 bf16_t* __restrict__ Kt) {
  int bz = blockIdx.z, bi = bz & 15, wsel = bz >> 4;   // 0..31
  int n0 = blockIdx.x * 128, m0 = blockIdx.y * 128;
  const bf16_t* A = hnT + (size_t)bi * NHW * NC;
  const bf16_t* B = Wt + (size_t)wsel * NC * NC;
  ACC_INIT(acc);
  gemm_core<NC, true>(A, B, m0, n0, acc);

  const int lane = threadIdx.x & 63, wv = threadIdx.x >> 6;
  const int l16 = lane & 15, quad = lane >> 4, wm = wv & 1, wn = wv >> 1;
  const float* bias = wsel ? b1 : b0;
  bf16_t* out = (wsel ? Kt : Qt) + (size_t)bi * NHW * NC;
#pragma unroll
  for (int i = 0; i < 4; i++) {
    int m = m0 + wm * 64 + i * 16 + l16;
#pragma unroll
    for (int j = 0; j < 4; j++) {
      int db = n0 + wn * 64 + j * 16 + quad * 4;
      float4 bv = *(const float4*)&bias[db];
      bf16x4 pk;
      pk[0] = (bf16_t)(acc[i][j][0] + bv.x);
      pk[1] = (bf16_t)(acc[i][j][1] + bv.y);
      pk[2] = (bf16_t)(acc[i][j][2] + bv.z);
      pk[3] = (bf16_t)(acc[i][j][3] + bv.w);
      *(bf16x4*)&out[(size_t)m * NC + db] = pk;
    }
  }
}

// ------------- V GEMM (no swap): Vm[d][n] packed along n -------------
__global__ __launch_bounds__(256) void gemm_v_k(const bf16_t* __restrict__ hnT,
                                                const bf16_t* __restrict__ Wt2,
                                                const float* __restrict__ b2,
                                                bf16_t* __restrict__ Vm) {
  int bi = blockIdx.z;
  int n0 = blockIdx.x * 128, m0 = blockIdx.y * 128;
  const bf16_t* A = hnT + (size_t)bi * NHW * NC;
  ACC_INIT(acc);
  gemm_core<NC, false>(A, Wt2, m0, n0, acc);

  const int lane = threadIdx.x & 63, wv = threadIdx.x >> 6;
  const int l16 = lane & 15, quad = lane >> 4, wm = wv & 1, wn = wv >> 1;
  bf16_t* out = Vm + (size_t)bi * NC * NHW;
#pragma unroll
  for (int i = 0; i < 4; i++)
#pragma unroll
    for (int j = 0; j < 4; j++) {
      int row = m0 + wm * 64 + i * 16 + quad * 4;   // spatial n
      int col = n0 + wn * 64 + j * 16 + l16;        // channel d
      float bv = b2[col];
      bf16x4 pk;
#pragma unroll
      for (int r = 0; r < 4; r++) pk[r] = (bf16_t)(acc[i][j][r] + bv);
      *(bf16x4*)&out[(size_t)col * NHW + row] = pk;
    }
}

// ------------- S GEMM (SWAP): S[i][j] (fp16) = SCALE*Q·K^T, packed 8B stores -------------
__global__ __launch_bounds__(256) void gemm_s_k(const bf16_t* __restrict__ Qt,
                                                const bf16_t* __restrict__ Kt,
                                                f16_t* __restrict__ S) {
  int bi = blockIdx.z;
  int n0 = blockIdx.x * 128, m0 = blockIdx.y * 128;
  const bf16_t* A = Qt + (size_t)bi * NHW * NC;
  const bf16_t* B = Kt + (size_t)bi * NHW * NC;
  ACC_INIT(acc);
  gemm_core<NC, true>(A, B, m0, n0, acc);

  const int lane = threadIdx.x & 63, wv = threadIdx.x >> 6;
  const int l16 = lane & 15, quad = lane >> 4, wm = wv & 1, wn = wv >> 1;
  f16_t* out = S + (size_t)bi * NHW * NHW;
#pragma unroll
  for (int i = 0; i < 4; i++) {
    int m = m0 + wm * 64 + i * 16 + l16;
#pragma unroll
    for (int j = 0; j < 4; j++) {
      int nb = n0 + wn * 64 + j * 16 + quad * 4;
      f16x4 pk;
#pragma unroll
      for (int r = 0; r < 4; r++) pk[r] = (f16_t)(acc[i][j][r] * SCALE);
      *(f16x4*)&out[(size_t)m * NHW + nb] = pk;
    }
  }
}

// ------------- softmax: one wave per row; P (bf16) overwrites S (fp16) in place -------------
__global__ __launch_bounds__(256) void softmax_k(const f16_t* __restrict__ S,
                                                 bf16_t* __restrict__ P) {
  int row = blockIdx.x * 4 + (threadIdx.x >> 6);
  int lane = threadIdx.x & 63;
  const f16_t* sp = S + (size_t)row * NHW + lane * 16;
  f16x8 a = *(const f16x8*)sp;
  f16x8 b = *(const f16x8*)(sp + 8);
  float v[16];
#pragma unroll
  for (int k = 0; k < 8; k++) { v[k] = (float)a[k]; v[8 + k] = (float)b[k]; }
  float mx = v[0];
#pragma unroll
  for (int k = 1; k < 16; k++) mx = fmaxf(mx, v[k]);
#pragma unroll
  for (int off = 1; off < 64; off <<= 1) mx = fmaxf(mx, __shfl_xor(mx, off, 64));
  float e[16], s = 0.f;
#pragma unroll
  for (int k = 0; k < 16; k++) { e[k] = exp2f((v[k] - mx) * LOG2E); s += e[k]; }
#pragma unroll
  for (int off = 1; off < 64; off <<= 1) s += __shfl_xor(s, off, 64);
  float inv = 1.f / s;
  bf16x8 o0, o1;
#pragma unroll
  for (int k = 0; k < 8; k++) { o0[k] = (bf16_t)(e[k] * inv); o1[k] = (bf16_t)(e[8 + k] * inv); }
  bf16_t* pp = P + (size_t)row * NHW + lane * 16;
  *(bf16x8*)pp = o0;
  *(bf16x8*)(pp + 8) = o1;
}

// ------------- PV GEMM (SWAP): Ot[i][c] = P[i][:]·Vm[c][:], K=1024, packed stores -------------
__global__ __launch_bounds__(256) void gemm_pv_k(const bf16_t* __restrict__ P,
                                                 const bf16_t* __restrict__ Vm,
                                                 bf16_t* __restrict__ Ot) {
  int bi = blockIdx.z;
  int n0 = blockIdx.x * 128, m0 = blockIdx.y * 128;
  const bf16_t* A = P + (size_t)bi * NHW * NHW;
  const bf16_t* B = Vm + (size_t)bi * NC * NHW;
  ACC_INIT(acc);
  gemm_core<NHW, true>(A, B, m0, n0, acc);

  const int lane = threadIdx.x & 63, wv = threadIdx.x >> 6;
  const int l16 = lane & 15, quad = lane >> 4, wm = wv & 1, wn = wv >> 1;
  bf16_t* out = Ot + (size_t)bi * NHW * NC;
#pragma unroll
  for (int i = 0; i < 4; i++) {
    int m = m0 + wm * 64 + i * 16 + l16;
#pragma unroll
    for (int j = 0; j < 4; j++) {
      int cb = n0 + wn * 64 + j * 16 + quad * 4;
      bf16x4 pk;
#pragma unroll
      for (int r = 0; r < 4; r++) pk[r] = (bf16_t)(acc[i][j][r]);
      *(bf16x4*)&out[(size_t)m * NC + cb] = pk;
    }
  }
}

// ------------- final GEMM + bias + residual: out[d][n] (fp32), float4 stores -------------
__global__ __launch_bounds__(256) void gemm_fin_k(const bf16_t* __restrict__ Ot,
                                                  const bf16_t* __restrict__ W3t,
                                                  const float* __restrict__ b3,
                                                  const float* __restrict__ x,
                                                  float* __restrict__ outp) {
  int bi = blockIdx.z;
  int n0 = blockIdx.x * 128, m0 = blockIdx.y * 128;
  const bf16_t* A = Ot + (size_t)bi * NHW * NC;
  ACC_INIT(acc);
  gemm_core<NC, false>(A, W3t, m0, n0, acc);

  const int lane = threadIdx.x & 63, wv = threadIdx.x >> 6;
  const int l16 = lane & 15, quad = lane >> 4, wm = wv & 1, wn = wv >> 1;
  const float* xb = x + (size_t)bi * NC * NHW;
  float* ob = outp + (size_t)bi * NC * NHW;
#pragma unroll
  for (int i = 0; i < 4; i++)
#pragma unroll
    for (int j = 0; j < 4; j++) {
      int row = m0 + wm * 64 + i * 16 + quad * 4;  // spatial n
      int col = n0 + wn * 64 + j * 16 + l16;       // channel d
      float bv = b3[col];
      size_t base = (size_t)col * NHW + row;
      float4 xv = *(const float4*)&xb[base];
      float4 pk;
      pk.x = acc[i][j][0] + bv + xv.x;
      pk.y = acc[i][j][1] + bv + xv.y;
      pk.z = acc[i][j][2] + bv + xv.z;
      pk.w = acc[i][j][3] + bv + xv.w;
      *(float4*)&ob[base] = pk;
    }
}

extern "C" void kernel_launch(void* const* d_in, const int* in_sizes, int n_in,
                              void* d_out, int out_size, void* d_ws, size_t ws_size,
                              hipStream_t stream) {
  (void)in_sizes; (void)n_in; (void)out_size; (void)ws_size;
  const float* x     = (const float*)d_in[0];
  const float* gamma = (const float*)d_in[1];
  const float* beta  = (const float*)d_in[2];
  const float* W0    = (const float*)d_in[3];
  const float* b0    = (const float*)d_in[4];
  const float* W1    = (const float*)d_in[5];
  const float* b1    = (const float*)d_in[6];
  const float* W2    = (const float*)d_in[7];
  const float* b2    = (const float*)d_in[8];
  const float* W3    = (const float*)d_in[9];
  const float* b3    = (const float*)d_in[10];
  float* outp = (float*)d_out;

  char* ws = (char*)d_ws;
  const size_t PLANE = (size_t)NB * NHW * NC * sizeof(bf16_t);  // 16 MB
  float* stats = (float*)ws;
  size_t off = 4096;
  bf16_t* hnT = (bf16_t*)(ws + off); off += PLANE;   // reused as Ot after PV
  bf16_t* Qt  = (bf16_t*)(ws + off); off += PLANE;
  bf16_t* Kt  = (bf16_t*)(ws + off); off += PLANE;
  bf16_t* Vm  = (bf16_t*)(ws + off); off += PLANE;
  bf16_t* Wt  = (bf16_t*)(ws + off); off += 4 * (size_t)NC * NC * sizeof(bf16_t);
  f16_t*  S   = (f16_t*)(ws + off);  off += (size_t)NB * NHW * NHW * sizeof(f16_t);  // 32 MB
  bf16_t* P   = (bf16_t*)S;  // softmax writes bf16 in place
  bf16_t* Ot  = hnT;         // hnT dead after V GEMM

  gn_stats_k<<<NB * NG, 256, 0, stream>>>(x, stats);
  gn_apply_k<<<dim3(32, 16, NB), 256, 0, stream>>>(x, gamma, beta, stats, hnT);
  wtrans_k<<<dim3(16, 16, 4), 256, 0, stream>>>(W0, W1, W2, W3, Wt);
  gemm_qk_k<<<dim3(4, 8, 32), 256, 0, stream>>>(hnT, Wt, b0, b1, Qt, Kt);
  gemm_v_k<<<dim3(4, 8, NB), 256, 0, stream>>>(hnT, Wt + 2 * (size_t)NC * NC, b2, Vm);
  gemm_s_k<<<dim3(8, 8, NB), 256, 0, stream>>>(Qt, Kt, S);
  softmax_k<<<dim3(NB * NHW / 4), 256, 0, stream>>>(S, P);
  gemm_pv_k<<<dim3(4, 8, NB), 256, 0, stream>>>(P, Vm, Ot);
  gemm_fin_k<<<dim3(4, 8, NB), 256, 0, stream>>>(Ot, Wt + 3 * (size_t)NC * NC, b3, x, outp);
}